// Round 6
// baseline (1275.367 us; speedup 1.0000x reference)
//
#include <hip/hip_runtime.h>

// GCN, 7 layers: h = relu(Â (h W) + b), Â = D^-1/2 (A + I) D^-1/2.
// Round 6: CSR fill write-amplification fix — two-pass bucketed scatter
// (pass A: scatter to 256-node bucket regions, sequential-ish streams;
// pass B: in-bucket (<=32KB, L2-resident) final placement). Also merges
// edge_deg+hist, dinv into scan1, bucket cursor init into scan3.

static constexpr int NN = 100000;
static constexpr int NE = 1600000;
static constexpr int NB = (NN + 255) / 256;  // 391 scan blocks == buckets

// ---------------- init: deg = 1 (self-loop), cnt = 0 ----------------

__global__ void k_init(float* __restrict__ deg, int* __restrict__ cnt) {
    int i = blockIdx.x * blockDim.x + threadIdx.x;
    if (i < NN) { deg[i] = 1.0f; cnt[i] = 0; }
}

// one edge pass: weighted degree + in-degree histogram
__global__ void k_deg_hist(const int* __restrict__ col, const float* __restrict__ w,
                           float* __restrict__ deg, int* __restrict__ cnt) {
    int e = blockIdx.x * blockDim.x + threadIdx.x;
    if (e >= NE) return;
    int c = col[e];
    atomicAdd(&deg[c], w[e]);
    atomicAdd(&cnt[c], 1);
}

// ---------------- scans (CSR offsets) + dinv ----------------

// per-block exclusive scan of cnt (in place) + block sums; also deg -> dinv
__global__ void k_scan1(int* __restrict__ cnt, int* __restrict__ bsum,
                        float* __restrict__ deg) {
    __shared__ int lds[256];
    int i = blockIdx.x * 256 + threadIdx.x;
    int v = (i < NN) ? cnt[i] : 0;
    if (i < NN) {
        float d = deg[i];
        deg[i] = (d > 0.0f) ? rsqrtf(d) : 0.0f;   // deg becomes dinv
    }
    lds[threadIdx.x] = v;
    __syncthreads();
    for (int off = 1; off < 256; off <<= 1) {
        int t = (threadIdx.x >= off) ? lds[threadIdx.x - off] : 0;
        __syncthreads();
        lds[threadIdx.x] += t;
        __syncthreads();
    }
    if (i < NN) cnt[i] = lds[threadIdx.x] - v;  // exclusive within block
    if (threadIdx.x == 255) bsum[blockIdx.x] = lds[255];
}

__global__ void k_scan2(int* __restrict__ bsum) {
    __shared__ int lds[512];
    int i = threadIdx.x;
    int v = (i < NB) ? bsum[i] : 0;
    lds[i] = v;
    __syncthreads();
    for (int off = 1; off < 512; off <<= 1) {
        int t = (i >= off) ? lds[i - off] : 0;
        __syncthreads();
        lds[i] += t;
        __syncthreads();
    }
    if (i < NB) bsum[i] = lds[i] - v;  // exclusive
}

// offs = in-block-exclusive + bsum[block]; seed per-node cursor and
// per-bucket cursor (bucket = 256 nodes -> bucket start = offs[256*B])
__global__ void k_scan3(const int* __restrict__ cnt, const int* __restrict__ bsum,
                        int* __restrict__ offs, int* __restrict__ cursor,
                        int* __restrict__ bcur) {
    int i = blockIdx.x * 256 + threadIdx.x;
    if (i < NN) {
        int o = cnt[i] + bsum[i >> 8];
        offs[i] = o;
        cursor[i] = o;
        if ((i & 255) == 0) bcur[i >> 8] = o;
    }
    if (i == 0) offs[NN] = NE;
}

// ---------------- two-pass bucketed CSR fill ----------------
// Pass A: scatter record to the destination's bucket region. 391 write
// streams advance sequentially -> lines fill before eviction.
__global__ void k_passA(const int* __restrict__ row, const int* __restrict__ col,
                        const float* __restrict__ ew, const float* __restrict__ dinv,
                        int* __restrict__ bcur, int* __restrict__ bc,
                        int2* __restrict__ bsw) {
    int e = blockIdx.x * blockDim.x + threadIdx.x;
    if (e >= NE) return;
    int r = row[e], c = col[e];
    float nw = dinv[r] * ew[e] * dinv[c];
    int p = atomicAdd(&bcur[c >> 8], 1);
    bc[p] = c;
    bsw[p] = make_int2(r, __float_as_int(nw));
}

// Pass B: in-bucket placement. p and q=cursor[c]++ are in the same <=32KB
// bucket region of csw -> L2 absorbs reordering, HBM write = 12.8 MB exact.
__global__ void k_passB(const int* __restrict__ bc, const int2* __restrict__ bsw,
                        int* __restrict__ cursor, int2* __restrict__ csw) {
    int p = blockIdx.x * blockDim.x + threadIdx.x;
    if (p >= NE) return;
    int c = bc[p];
    int q = atomicAdd(&cursor[c], 1);
    csw[q] = bsw[p];
}

// ---------------- dense H = X * W ----------------
// Thread per node; acc[FOUT] in VGPRs; W loop-uniform -> s_load scalar reads.

template <int FIN, int FOUT>
__global__ __launch_bounds__(256) void k_matmul(const float* __restrict__ X,
                                                const float* __restrict__ W,
                                                float* __restrict__ H) {
    int i = blockIdx.x * 256 + threadIdx.x;
    if (i >= NN) return;
    const float* xr = X + (size_t)i * FIN;
    float acc[FOUT];
#pragma unroll
    for (int j = 0; j < FOUT; ++j) acc[j] = 0.0f;

    constexpr int KV = (FIN % 4 == 0) ? 4 : 2;
    for (int k = 0; k < FIN; k += KV) {
        float xv[KV];
        if constexpr (KV == 4) *(float4*)xv = *(const float4*)(xr + k);
        else                   *(float2*)xv = *(const float2*)(xr + k);
#pragma unroll
        for (int kk = 0; kk < KV; ++kk)
#pragma unroll
            for (int j = 0; j < FOUT; ++j)
                acc[j] = fmaf(xv[kk], W[(k + kk) * FOUT + j], acc[j]);
    }
    float* hr = H + (size_t)i * FOUT;
#pragma unroll
    for (int j = 0; j < FOUT; ++j) hr[j] = acc[j];
}

template <int FIN>
__global__ void k_matmul_1(const float* __restrict__ X, const float* __restrict__ W,
                           float* __restrict__ H) {
    int i = blockIdx.x * blockDim.x + threadIdx.x;
    if (i >= NN) return;
    const float* xr = X + (size_t)i * FIN;
    float acc = 0.0f;
#pragma unroll
    for (int k = 0; k < FIN; k += 2) {
        float2 xv = *(const float2*)(xr + k);
        acc = fmaf(xv.x, W[k], acc);
        acc = fmaf(xv.y, W[k + 1], acc);
    }
    H[i] = acc;
}

// ---------------- CSR pull aggregation + fused epilogue ----------------

template <int F, int LPN, bool RELU>
__global__ __launch_bounds__(256) void k_agg2(const int* __restrict__ offs,
                                              const int2* __restrict__ csw,
                                              const float* __restrict__ H,
                                              const float* __restrict__ dinv,
                                              const float* __restrict__ b,
                                              float* __restrict__ O) {
    constexpr int FH = F / 2;
    int t = blockIdx.x * blockDim.x + threadIdx.x;
    int g = t / LPN;
    int f = t - g * LPN;           // float2 lane
    if (g >= NN || f >= FH) return;
    int p = offs[g];
    const int pe = offs[g + 1];

    float2 a0 = {0.f, 0.f}, a1 = {0.f, 0.f}, a2 = {0.f, 0.f}, a3 = {0.f, 0.f};

    if (p < pe && (p & 1)) {       // peel to even p for 16B-aligned int4 loads
        int2 e = csw[p];
        float2 h = *(const float2*)(H + (size_t)e.x * F + 2 * f);
        float w = __int_as_float(e.y);
        a0.x = fmaf(h.x, w, a0.x); a0.y = fmaf(h.y, w, a0.y);
        ++p;
    }
    for (; p + 4 <= pe; p += 4) {
        int4 e01 = *(const int4*)(csw + p);
        int4 e23 = *(const int4*)(csw + p + 2);
        float2 h0 = *(const float2*)(H + (size_t)e01.x * F + 2 * f);
        float2 h1 = *(const float2*)(H + (size_t)e01.z * F + 2 * f);
        float2 h2 = *(const float2*)(H + (size_t)e23.x * F + 2 * f);
        float2 h3 = *(const float2*)(H + (size_t)e23.z * F + 2 * f);
        float w0 = __int_as_float(e01.y), w1 = __int_as_float(e01.w);
        float w2 = __int_as_float(e23.y), w3 = __int_as_float(e23.w);
        a0.x = fmaf(h0.x, w0, a0.x); a0.y = fmaf(h0.y, w0, a0.y);
        a1.x = fmaf(h1.x, w1, a1.x); a1.y = fmaf(h1.y, w1, a1.y);
        a2.x = fmaf(h2.x, w2, a2.x); a2.y = fmaf(h2.y, w2, a2.y);
        a3.x = fmaf(h3.x, w3, a3.x); a3.y = fmaf(h3.y, w3, a3.y);
    }
    for (; p < pe; ++p) {
        int2 e = csw[p];
        float2 h = *(const float2*)(H + (size_t)e.x * F + 2 * f);
        float w = __int_as_float(e.y);
        a0.x = fmaf(h.x, w, a0.x); a0.y = fmaf(h.y, w, a0.y);
    }

    float di = dinv[g];
    float d2 = di * di;
    float2 hs = *(const float2*)(H + (size_t)g * F + 2 * f);
    float2 bb = *(const float2*)(b + 2 * f);
    float vx = ((a0.x + a1.x) + (a2.x + a3.x)) + fmaf(hs.x, d2, bb.x);
    float vy = ((a0.y + a1.y) + (a2.y + a3.y)) + fmaf(hs.y, d2, bb.y);
    if (RELU) { vx = fmaxf(vx, 0.0f); vy = fmaxf(vy, 0.0f); }
    *(float2*)(O + (size_t)g * F + 2 * f) = make_float2(vx, vy);
}

__global__ void k_agg1(const int* __restrict__ offs, const int2* __restrict__ csw,
                       const float* __restrict__ H, const float* __restrict__ dinv,
                       const float* __restrict__ b, float* __restrict__ O) {
    int g = blockIdx.x * blockDim.x + threadIdx.x;
    if (g >= NN) return;
    int p = offs[g];
    const int pe = offs[g + 1];
    float a0 = 0.f, a1 = 0.f, a2 = 0.f, a3 = 0.f;
    for (; p + 4 <= pe; p += 4) {
        int2 e0 = csw[p], e1 = csw[p + 1], e2 = csw[p + 2], e3 = csw[p + 3];
        a0 = fmaf(H[e0.x], __int_as_float(e0.y), a0);
        a1 = fmaf(H[e1.x], __int_as_float(e1.y), a1);
        a2 = fmaf(H[e2.x], __int_as_float(e2.y), a2);
        a3 = fmaf(H[e3.x], __int_as_float(e3.y), a3);
    }
    for (; p < pe; ++p) {
        int2 e0 = csw[p];
        a0 = fmaf(H[e0.x], __int_as_float(e0.y), a0);
    }
    float di = dinv[g];
    O[g] = ((a0 + a1) + (a2 + a3)) + fmaf(H[g], di * di, b[0]);
}

// ---------------- launch ----------------

static inline size_t alignup(size_t x) { return (x + 255) & ~(size_t)255; }

extern "C" void kernel_launch(void* const* d_in, const int* in_sizes, int n_in,
                              void* d_out, int out_size, void* d_ws, size_t ws_size,
                              hipStream_t stream) {
    const float* x  = (const float*)d_in[0];
    const int*   ei = (const int*)d_in[1];
    const float* ew = (const float*)d_in[2];
    const float* Wp[7];
    const float* Bp[7];
    for (int l = 0; l < 7; ++l) {
        Wp[l] = (const float*)d_in[3 + 2 * l];
        Bp[l] = (const float*)d_in[4 + 2 * l];
    }
    const int* row = ei;       // source
    const int* col = ei + NE;  // destination

    // workspace carve (~101 MB)
    char* ws = (char*)d_ws;
    float* dinv  = (float*)ws;  ws += alignup((size_t)NN * 4);
    float* Hb    = (float*)ws;  ws += alignup((size_t)NN * 50 * 4);
    float* Aa    = (float*)ws;  ws += alignup((size_t)NN * 50 * 4);
    float* Ab    = (float*)ws;  ws += alignup((size_t)NN * 50 * 4);
    int*   cnt   = (int*)ws;    ws += alignup((size_t)NN * 4);
    int*   offs  = (int*)ws;    ws += alignup((size_t)(NN + 1) * 4);
    int*   cursor= (int*)ws;    ws += alignup((size_t)NN * 4);
    int*   bsum  = (int*)ws;    ws += alignup((size_t)NB * 4);
    int*   bcur  = (int*)ws;    ws += alignup((size_t)NB * 4);
    int*   bc    = (int*)ws;    ws += alignup((size_t)NE * 4);
    int2*  bsw   = (int2*)ws;   ws += alignup((size_t)NE * 8);
    int2*  csw   = (int2*)ws;   ws += alignup((size_t)NE * 8);

    const int gN = (NN + 255) / 256;
    const int gE = (NE + 255) / 256;

    // degree + histogram (one edge pass), then dinv + CSR offsets
    k_init<<<gN, 256, 0, stream>>>(dinv, cnt);
    k_deg_hist<<<gE, 256, 0, stream>>>(col, ew, dinv, cnt);
    k_scan1<<<NB, 256, 0, stream>>>(cnt, bsum, dinv);
    k_scan2<<<1, 512, 0, stream>>>(bsum);
    k_scan3<<<NB, 256, 0, stream>>>(cnt, bsum, offs, cursor, bcur);

    // two-pass bucketed CSR fill
    k_passA<<<gE, 256, 0, stream>>>(row, col, ew, dinv, bcur, bc, bsw);
    k_passB<<<gE, 256, 0, stream>>>(bc, bsw, cursor, csw);

#define LAYER(FIN, FOUT, LPN, RELU, XIN, OUT, LIDX)                                         \
    do {                                                                                    \
        k_matmul<FIN, FOUT><<<gN, 256, 0, stream>>>((XIN), Wp[LIDX], Hb);                   \
        k_agg2<FOUT, LPN, RELU><<<((size_t)NN * (LPN) + 255) / 256, 256, 0, stream>>>(      \
            offs, csw, Hb, dinv, Bp[LIDX], (OUT));                                          \
    } while (0)

    LAYER(128, 50, 32, true, x,  Aa, 0);
    LAYER(50,  50, 32, true, Aa, Ab, 1);
    LAYER(50,  30, 16, true, Ab, Aa, 2);
    LAYER(30,  30, 16, true, Aa, Ab, 3);
    LAYER(30,  10, 8,  true, Ab, Aa, 4);
    LAYER(10,  10, 8,  true, Aa, Ab, 5);
#undef LAYER

    // layer 7: 10 -> 1, no relu
    k_matmul_1<10><<<gN, 256, 0, stream>>>(Ab, Wp[6], Hb);
    k_agg1<<<gN, 256, 0, stream>>>(offs, csw, Hb, dinv, Bp[6], (float*)d_out);
}

// Round 7
// 840.787 us; speedup vs baseline: 1.5169x; 1.5169x over previous
//
#include <hip/hip_runtime.h>

// GCN, 7 layers: h = relu(Â (h W) + b), Â = D^-1/2 (A + I) D^-1/2.
// Round 7: revert round-6's contended-bucket scatter (558 µs, atomic-queueing
// bound on 391 shared counters). CSR fill now: LDS-histogram + deterministic
// range reservation (scan, no global atomics) + contiguous staged writes +
// L2-local final placement with per-node cursors (100k addrs, ~16 atomics
// each — proven uncontended in r5).

static constexpr int NN = 100000;
static constexpr int NE = 1600000;
static constexpr int NB = (NN + 255) / 256;        // 391 node-scan blocks
static constexpr int NBUK = (NN + 2047) >> 11;     // 49 buckets (2048 nodes)
static constexpr int EPT = 8;                      // edges per thread (A0/A1)
static constexpr int EB = (NE + 2047) / 2048;      // 782 edge blocks
static constexpr int SCAN_N = NBUK * EB;           // 38318

// ---------------- init: deg = 1 (self-loop), cnt = 0 ----------------

__global__ void k_init(float* __restrict__ deg, int* __restrict__ cnt) {
    int i = blockIdx.x * blockDim.x + threadIdx.x;
    if (i < NN) { deg[i] = 1.0f; cnt[i] = 0; }
}

// ---------------- A0: weighted degree + node histogram + bucket counts ----

__global__ __launch_bounds__(256) void k_A0(const int* __restrict__ col,
                                            const float* __restrict__ ew,
                                            float* __restrict__ deg,
                                            int* __restrict__ cnt,
                                            int* __restrict__ counts) {
    __shared__ int lh[NBUK];
    for (int j = threadIdx.x; j < NBUK; j += 256) lh[j] = 0;
    __syncthreads();
    int base = blockIdx.x * 2048;
#pragma unroll
    for (int k = 0; k < EPT; ++k) {
        int e = base + k * 256 + threadIdx.x;
        if (e < NE) {
            int c = col[e];
            atomicAdd(&deg[c], ew[e]);
            atomicAdd(&cnt[c], 1);
            atomicAdd(&lh[c >> 11], 1);
        }
    }
    __syncthreads();
    for (int j = threadIdx.x; j < NBUK; j += 256)
        counts[j * EB + blockIdx.x] = lh[j];  // bucket-major for the scan
}

// ---------------- scans ----------------

// per-block exclusive scan of cnt (in place) + block sums; deg -> dinv
__global__ void k_scan1(int* __restrict__ cnt, int* __restrict__ bsum,
                        float* __restrict__ deg) {
    __shared__ int lds[256];
    int i = blockIdx.x * 256 + threadIdx.x;
    int v = (i < NN) ? cnt[i] : 0;
    if (i < NN) {
        float d = deg[i];
        deg[i] = (d > 0.0f) ? rsqrtf(d) : 0.0f;   // deg becomes dinv
    }
    lds[threadIdx.x] = v;
    __syncthreads();
    for (int off = 1; off < 256; off <<= 1) {
        int t = (threadIdx.x >= off) ? lds[threadIdx.x - off] : 0;
        __syncthreads();
        lds[threadIdx.x] += t;
        __syncthreads();
    }
    if (i < NN) cnt[i] = lds[threadIdx.x] - v;  // exclusive within block
    if (threadIdx.x == 255) bsum[blockIdx.x] = lds[255];
}

__global__ void k_scan2(int* __restrict__ bsum) {
    __shared__ int lds[512];
    int i = threadIdx.x;
    int v = (i < NB) ? bsum[i] : 0;
    lds[i] = v;
    __syncthreads();
    for (int off = 1; off < 512; off <<= 1) {
        int t = (i >= off) ? lds[i - off] : 0;
        __syncthreads();
        lds[i] += t;
        __syncthreads();
    }
    if (i < NB) bsum[i] = lds[i] - v;  // exclusive
}

__global__ void k_scan3(const int* __restrict__ cnt, const int* __restrict__ bsum,
                        int* __restrict__ offs, int* __restrict__ cursor) {
    int i = blockIdx.x * 256 + threadIdx.x;
    if (i < NN) {
        int o = cnt[i] + bsum[i >> 8];
        offs[i] = o;
        cursor[i] = o;
    }
    if (i == 0) offs[NN] = NE;
}

// single-block exclusive scan of counts[SCAN_N] (bucket-major) -> start offsets
__global__ __launch_bounds__(1024) void k_bbscan(int* __restrict__ counts) {
    __shared__ int lds[1024];
    const int t = threadIdx.x;
    const int per = (SCAN_N + 1023) / 1024;  // 38
    const int base = t * per;
    int s = 0;
    for (int k = 0; k < per; ++k) {
        int idx = base + k;
        if (idx < SCAN_N) s += counts[idx];
    }
    lds[t] = s;
    __syncthreads();
    for (int off = 1; off < 1024; off <<= 1) {
        int v = (t >= off) ? lds[t - off] : 0;
        __syncthreads();
        lds[t] += v;
        __syncthreads();
    }
    int run = lds[t] - s;  // exclusive prefix of this thread's chunk
    for (int k = 0; k < per; ++k) {
        int idx = base + k;
        if (idx < SCAN_N) { int c = counts[idx]; counts[idx] = run; run += c; }
    }
}

// ---------------- A1: staged bucket-grouped write (LDS cursors) ----------

__global__ __launch_bounds__(256) void k_A1(const int* __restrict__ row,
                                            const int* __restrict__ col,
                                            const float* __restrict__ ew,
                                            const float* __restrict__ dinv,
                                            const int* __restrict__ counts,
                                            int4* __restrict__ stg) {
    __shared__ int cur[NBUK];
    for (int j = threadIdx.x; j < NBUK; j += 256)
        cur[j] = counts[j * EB + blockIdx.x];
    __syncthreads();
    int base = blockIdx.x * 2048;
#pragma unroll
    for (int k = 0; k < EPT; ++k) {
        int e = base + k * 256 + threadIdx.x;
        if (e < NE) {
            int c = col[e], r = row[e];
            float nw = dinv[r] * ew[e] * dinv[c];
            int pos = atomicAdd(&cur[c >> 11], 1);  // LDS atomic, returns old
            stg[pos] = make_int4(c, r, __float_as_int(nw), 0);
        }
    }
}

// ---------------- B: final CSR placement (L2-local per bucket) ----------

__global__ void k_B(const int4* __restrict__ stg, int* __restrict__ cursor,
                    int2* __restrict__ csw) {
    int p = blockIdx.x * blockDim.x + threadIdx.x;
    if (p >= NE) return;
    int4 s = stg[p];
    int q = atomicAdd(&cursor[s.x], 1);
    csw[q] = make_int2(s.y, s.z);
}

// ---------------- dense H = X * W ----------------
// Thread per node; acc[FOUT] in VGPRs; W loop-uniform -> s_load scalar reads.

template <int FIN, int FOUT>
__global__ __launch_bounds__(256) void k_matmul(const float* __restrict__ X,
                                                const float* __restrict__ W,
                                                float* __restrict__ H) {
    int i = blockIdx.x * 256 + threadIdx.x;
    if (i >= NN) return;
    const float* xr = X + (size_t)i * FIN;
    float acc[FOUT];
#pragma unroll
    for (int j = 0; j < FOUT; ++j) acc[j] = 0.0f;

    constexpr int KV = (FIN % 4 == 0) ? 4 : 2;
    for (int k = 0; k < FIN; k += KV) {
        float xv[KV];
        if constexpr (KV == 4) *(float4*)xv = *(const float4*)(xr + k);
        else                   *(float2*)xv = *(const float2*)(xr + k);
#pragma unroll
        for (int kk = 0; kk < KV; ++kk)
#pragma unroll
            for (int j = 0; j < FOUT; ++j)
                acc[j] = fmaf(xv[kk], W[(k + kk) * FOUT + j], acc[j]);
    }
    float* hr = H + (size_t)i * FOUT;
#pragma unroll
    for (int j = 0; j < FOUT; ++j) hr[j] = acc[j];
}

template <int FIN>
__global__ void k_matmul_1(const float* __restrict__ X, const float* __restrict__ W,
                           float* __restrict__ H) {
    int i = blockIdx.x * blockDim.x + threadIdx.x;
    if (i >= NN) return;
    const float* xr = X + (size_t)i * FIN;
    float acc = 0.0f;
#pragma unroll
    for (int k = 0; k < FIN; k += 2) {
        float2 xv = *(const float2*)(xr + k);
        acc = fmaf(xv.x, W[k], acc);
        acc = fmaf(xv.y, W[k + 1], acc);
    }
    H[i] = acc;
}

// ---------------- CSR pull aggregation + fused epilogue ----------------

template <int F, int LPN, bool RELU>
__global__ __launch_bounds__(256) void k_agg2(const int* __restrict__ offs,
                                              const int2* __restrict__ csw,
                                              const float* __restrict__ H,
                                              const float* __restrict__ dinv,
                                              const float* __restrict__ b,
                                              float* __restrict__ O) {
    constexpr int FH = F / 2;
    int t = blockIdx.x * blockDim.x + threadIdx.x;
    int g = t / LPN;
    int f = t - g * LPN;           // float2 lane
    if (g >= NN || f >= FH) return;
    int p = offs[g];
    const int pe = offs[g + 1];

    float2 a0 = {0.f, 0.f}, a1 = {0.f, 0.f}, a2 = {0.f, 0.f}, a3 = {0.f, 0.f};

    if (p < pe && (p & 1)) {       // peel to even p for 16B-aligned int4 loads
        int2 e = csw[p];
        float2 h = *(const float2*)(H + (size_t)e.x * F + 2 * f);
        float w = __int_as_float(e.y);
        a0.x = fmaf(h.x, w, a0.x); a0.y = fmaf(h.y, w, a0.y);
        ++p;
    }
    for (; p + 4 <= pe; p += 4) {
        int4 e01 = *(const int4*)(csw + p);
        int4 e23 = *(const int4*)(csw + p + 2);
        float2 h0 = *(const float2*)(H + (size_t)e01.x * F + 2 * f);
        float2 h1 = *(const float2*)(H + (size_t)e01.z * F + 2 * f);
        float2 h2 = *(const float2*)(H + (size_t)e23.x * F + 2 * f);
        float2 h3 = *(const float2*)(H + (size_t)e23.z * F + 2 * f);
        float w0 = __int_as_float(e01.y), w1 = __int_as_float(e01.w);
        float w2 = __int_as_float(e23.y), w3 = __int_as_float(e23.w);
        a0.x = fmaf(h0.x, w0, a0.x); a0.y = fmaf(h0.y, w0, a0.y);
        a1.x = fmaf(h1.x, w1, a1.x); a1.y = fmaf(h1.y, w1, a1.y);
        a2.x = fmaf(h2.x, w2, a2.x); a2.y = fmaf(h2.y, w2, a2.y);
        a3.x = fmaf(h3.x, w3, a3.x); a3.y = fmaf(h3.y, w3, a3.y);
    }
    for (; p < pe; ++p) {
        int2 e = csw[p];
        float2 h = *(const float2*)(H + (size_t)e.x * F + 2 * f);
        float w = __int_as_float(e.y);
        a0.x = fmaf(h.x, w, a0.x); a0.y = fmaf(h.y, w, a0.y);
    }

    float di = dinv[g];
    float d2 = di * di;
    float2 hs = *(const float2*)(H + (size_t)g * F + 2 * f);
    float2 bb = *(const float2*)(b + 2 * f);
    float vx = ((a0.x + a1.x) + (a2.x + a3.x)) + fmaf(hs.x, d2, bb.x);
    float vy = ((a0.y + a1.y) + (a2.y + a3.y)) + fmaf(hs.y, d2, bb.y);
    if (RELU) { vx = fmaxf(vx, 0.0f); vy = fmaxf(vy, 0.0f); }
    *(float2*)(O + (size_t)g * F + 2 * f) = make_float2(vx, vy);
}

__global__ void k_agg1(const int* __restrict__ offs, const int2* __restrict__ csw,
                       const float* __restrict__ H, const float* __restrict__ dinv,
                       const float* __restrict__ b, float* __restrict__ O) {
    int g = blockIdx.x * blockDim.x + threadIdx.x;
    if (g >= NN) return;
    int p = offs[g];
    const int pe = offs[g + 1];
    float a0 = 0.f, a1 = 0.f, a2 = 0.f, a3 = 0.f;
    for (; p + 4 <= pe; p += 4) {
        int2 e0 = csw[p], e1 = csw[p + 1], e2 = csw[p + 2], e3 = csw[p + 3];
        a0 = fmaf(H[e0.x], __int_as_float(e0.y), a0);
        a1 = fmaf(H[e1.x], __int_as_float(e1.y), a1);
        a2 = fmaf(H[e2.x], __int_as_float(e2.y), a2);
        a3 = fmaf(H[e3.x], __int_as_float(e3.y), a3);
    }
    for (; p < pe; ++p) {
        int2 e0 = csw[p];
        a0 = fmaf(H[e0.x], __int_as_float(e0.y), a0);
    }
    float di = dinv[g];
    O[g] = ((a0 + a1) + (a2 + a3)) + fmaf(H[g], di * di, b[0]);
}

// ---------------- launch ----------------

static inline size_t alignup(size_t x) { return (x + 255) & ~(size_t)255; }

extern "C" void kernel_launch(void* const* d_in, const int* in_sizes, int n_in,
                              void* d_out, int out_size, void* d_ws, size_t ws_size,
                              hipStream_t stream) {
    const float* x  = (const float*)d_in[0];
    const int*   ei = (const int*)d_in[1];
    const float* ew = (const float*)d_in[2];
    const float* Wp[7];
    const float* Bp[7];
    for (int l = 0; l < 7; ++l) {
        Wp[l] = (const float*)d_in[3 + 2 * l];
        Bp[l] = (const float*)d_in[4 + 2 * l];
    }
    const int* row = ei;       // source
    const int* col = ei + NE;  // destination

    // workspace carve (~100 MB)
    char* ws = (char*)d_ws;
    float* dinv  = (float*)ws;  ws += alignup((size_t)NN * 4);
    float* Hb    = (float*)ws;  ws += alignup((size_t)NN * 50 * 4);
    float* Aa    = (float*)ws;  ws += alignup((size_t)NN * 50 * 4);
    float* Ab    = (float*)ws;  ws += alignup((size_t)NN * 50 * 4);
    int*   cnt   = (int*)ws;    ws += alignup((size_t)NN * 4);
    int*   offs  = (int*)ws;    ws += alignup((size_t)(NN + 1) * 4);
    int*   cursor= (int*)ws;    ws += alignup((size_t)NN * 4);
    int*   bsum  = (int*)ws;    ws += alignup((size_t)NB * 4);
    int*   counts= (int*)ws;    ws += alignup((size_t)SCAN_N * 4);
    int4*  stg   = (int4*)ws;   ws += alignup((size_t)NE * 16);
    int2*  csw   = (int2*)ws;   ws += alignup((size_t)NE * 8);

    const int gN = (NN + 255) / 256;
    const int gE = (NE + 255) / 256;

    // degree + node histogram + per-(bucket,block) counts in one edge pass
    k_init<<<gN, 256, 0, stream>>>(dinv, cnt);
    k_A0<<<EB, 256, 0, stream>>>(col, ew, dinv, cnt, counts);
    k_scan1<<<NB, 256, 0, stream>>>(cnt, bsum, dinv);
    k_scan2<<<1, 512, 0, stream>>>(bsum);
    k_scan3<<<NB, 256, 0, stream>>>(cnt, bsum, offs, cursor);
    k_bbscan<<<1, 1024, 0, stream>>>(counts);

    // staged bucket-grouped write, then L2-local final placement
    k_A1<<<EB, 256, 0, stream>>>(row, col, ew, dinv, counts, stg);
    k_B<<<gE, 256, 0, stream>>>(stg, cursor, csw);

#define LAYER(FIN, FOUT, LPN, RELU, XIN, OUT, LIDX)                                         \
    do {                                                                                    \
        k_matmul<FIN, FOUT><<<gN, 256, 0, stream>>>((XIN), Wp[LIDX], Hb);                   \
        k_agg2<FOUT, LPN, RELU><<<((size_t)NN * (LPN) + 255) / 256, 256, 0, stream>>>(      \
            offs, csw, Hb, dinv, Bp[LIDX], (OUT));                                          \
    } while (0)

    LAYER(128, 50, 32, true, x,  Aa, 0);
    LAYER(50,  50, 32, true, Aa, Ab, 1);
    LAYER(50,  30, 16, true, Ab, Aa, 2);
    LAYER(30,  30, 16, true, Aa, Ab, 3);
    LAYER(30,  10, 8,  true, Ab, Aa, 4);
    LAYER(10,  10, 8,  true, Aa, Ab, 5);
#undef LAYER

    // layer 7: 10 -> 1, no relu
    k_matmul_1<10><<<gN, 256, 0, stream>>>(Ab, Wp[6], Hb);
    k_agg1<<<gN, 256, 0, stream>>>(offs, csw, Hb, dinv, Bp[6], (float*)d_out);
}